// Round 24
// baseline (26.288 us; speedup 1.0000x reference)
//
#include <hip/hip_runtime.h>

#define Bb 128
#define Ww 128
#define Nn 512
#define ALPHA 0.2f
#define LOG2E 1.44269504088896340736f

typedef __attribute__((ext_vector_type(8))) short short8;
typedef __attribute__((ext_vector_type(4))) float f32x4;

// v_cvt_pk_bf16_f32: packs (lo,hi) -> u32 of 2 bf16 (RNE; proven R9-R22)
__device__ __forceinline__ unsigned pk_bf16(float lo, float hi) {
  unsigned r;
  asm("v_cvt_pk_bf16_f32 %0, %1, %2" : "=v"(r) : "v"(lo), "v"(hi));
  return r;
}

// v_exp_f32 computes 2^x on gfx950 (proven R13-R22)
__device__ __forceinline__ float v_exp2(float x) {
  float r;
  asm("v_exp_f32 %0, %1" : "=v"(r) : "v"(x));
  return r;
}

// v_rcp_f32: ~1ulp reciprocal (proven R18-R22)
__device__ __forceinline__ float v_rcp(float x) {
  float r;
  asm("v_rcp_f32 %0, %1" : "=v"(r) : "v"(x));
  return r;
}

// ---- dynamic LDS layout (bytes) ---- (R20/R22 verbatim)
#define T_OFF   0
#define T_BYTES (64 * 129 * 8 * 2)     // ushort tile[64 jg][129 w][8] = 132096
#define SR_OFF  (T_OFF + T_BYTES)      // float sred[4096] = 16384
#define S1_OFF  (SR_OFF + 16384)       // float s1s[512]   = 2048
#define S2_OFF  (S1_OFF + 2048)        // float s2s[512]   = 2048
#define CV_OFF  (S2_OFF + 2048)        // float cvs[129]   (pad 528)
#define CP_OFF  (CV_OFF + 528)         // float cpart[1024] = 4096
#define SMEM15  (CP_OFF + 4096)        // 157200 < 163840

// One block = (batch b, i-half). 1024 threads = 16 waves = 4 waves/SIMD.
// R22 (best, 25.9us) + two zero-arithmetic scheduling hints:
//   (1) s_setprio(1) around the MFMA cluster (P4 is barrier-free -> waves at
//       different phases; prioritize the MFMA-issuing ones — T5 regime),
//   (2) non-temporal epilogue stores via ext-vector f32x4 (out never re-read).
__launch_bounds__(1024, 1)
__global__ void attn_p(const float* __restrict__ x, const float* __restrict__ Wfc,
                       const float* __restrict__ bfc, const float* __restrict__ attn,
                       float* __restrict__ out) {
  extern __shared__ char smem[];
  ushort* tile  = (ushort*)(smem + T_OFF);
  float*  sred  = (float*)(smem + SR_OFF);
  float*  s1s   = (float*)(smem + S1_OFF);
  float*  s2s   = (float*)(smem + S2_OFF);
  float*  cvs   = (float*)(smem + CV_OFF);
  float*  cpart = (float*)(smem + CP_OFF);

  const int bid = blockIdx.x;
  const int xcd = bid & 7, idx = bid >> 3;
  const int b  = xcd * 16 + (idx >> 1);      // sibling i-half blocks share an XCD/L2
  const int i0 = (idx & 1) * 256;
  const int t  = threadIdx.x;                // 0..1023
  const int wvw = t >> 6;                    // wave 0..15
  const int lane = t & 63;
  const int wl = lane & 15, lg = lane >> 4;
  const int g  = t >> 7;                     // row-group 0..7 (wave-uniform)
  const int q2 = t & 127;                    // col-slice (4 floats)
  const float* xb = x + (size_t)b * (Ww * Nn);

  // ---- issue group 1 (oldest): Wfc column slice + c0 inputs ----
  float wreg[16];
#pragma unroll
  for (int vi = 0; vi < 16; ++vi)
    wreg[vi] = Wfc[(size_t)(g * 16 + vi) * Ww + q2];
  float c0p = 0.f;
  if (t < 64)
    c0p = fmaf(bfc[t], attn[Ww + t], bfc[t + 64] * attn[Ww + 64 + t]);
  __builtin_amdgcn_sched_barrier(0);   // pin: group 1 issued before x

  // ---- issue group 2: ALL 16 x float4 loads (rows g+8k, cols 4*q2) ----
  float4 L[16];
#pragma unroll
  for (int k = 0; k < 16; ++k)
    L[k] = *reinterpret_cast<const float4*>(xb + (size_t)(g + 8 * k) * Nn + 4 * q2);
  __builtin_amdgcn_sched_barrier(0);   // pin: x issued before wreg consumption

  // ---- cvec partials from wreg: waits vmcnt(16), x stays in flight ----
  {
    float cp = 0.f;
#pragma unroll
    for (int vi = 0; vi < 16; ++vi)
      cp = fmaf(attn[Ww + g * 16 + vi], wreg[vi], cp);   // attn[..] wave-uniform
    cpart[t] = cp;                     // partial for col q2 from group g
    if (t < 64) {
      float cc = c0p;
#pragma unroll
      for (int off = 32; off; off >>= 1) cc += __shfl_xor(cc, off);
      if (t == 0) cvs[Ww] = cc;
    }
  }

  // ---- drain x: s1 partials + bf16 tile write ----
  float s1p[4] = {0.f, 0.f, 0.f, 0.f};
#pragma unroll
  for (int k = 0; k < 16; ++k) {
    const int w = g + 8 * k;
    const float aw = attn[w];          // wave-uniform -> s_load
    const float4 v = L[k];
    s1p[0] = fmaf(v.x, aw, s1p[0]); s1p[1] = fmaf(v.y, aw, s1p[1]);
    s1p[2] = fmaf(v.z, aw, s1p[2]); s1p[3] = fmaf(v.w, aw, s1p[3]);
    uint2 pk;
    pk.x = pk_bf16(v.x, v.y);
    pk.y = pk_bf16(v.z, v.w);
    *reinterpret_cast<uint2*>(tile + ((size_t)(q2 >> 1) * 129 + w) * 8 + (q2 & 1) * 4) = pk;
  }
  *reinterpret_cast<f32x4*>(&sred[t * 4]) = (f32x4){s1p[0], s1p[1], s1p[2], s1p[3]};
  __syncthreads();                     // BAR1: cpart + sred(s1) + tile visible

  // ---- cvs reduce (t<128) + s1 reduce (t<512) ----
  if (t < Ww) {
    float s = 0.f;
#pragma unroll
    for (int j = 0; j < 8; ++j) s += cpart[t + 128 * j];
    cvs[t] = s;
  }
  float red = 0.f;
  if (t < 512) {
#pragma unroll
    for (int j = 0; j < 8; ++j) red += sred[j * 512 + t];
  }
  __syncthreads();                     // BAR2: sred(s1) reads done; cvs visible
  if (t < 512) s1s[t] = red * LOG2E;

  // ---- s2 partials from the register-held x (no reload) ----
  float s2p[4] = {0.f, 0.f, 0.f, 0.f};
#pragma unroll
  for (int k = 0; k < 16; ++k) {
    const int w = g + 8 * k;
    const float cw = cvs[w];
    const float4 v = L[k];
    s2p[0] = fmaf(v.x, cw, s2p[0]); s2p[1] = fmaf(v.y, cw, s2p[1]);
    s2p[2] = fmaf(v.z, cw, s2p[2]); s2p[3] = fmaf(v.w, cw, s2p[3]);
  }
  *reinterpret_cast<f32x4*>(&sred[t * 4]) = (f32x4){s2p[0], s2p[1], s2p[2], s2p[3]};
  __syncthreads();                     // BAR3: sred(s2) visible
  if (t < 512) {
    float d = 0.f;
#pragma unroll
    for (int j = 0; j < 8; ++j) d += sred[j * 512 + t];
    s2s[t] = (d + cvs[Ww]) * LOG2E;
  }
  __syncthreads();                     // BAR4: s2s ready

  // ---- P4: MFMA loop (barrier-free); setprio around the MFMA cluster ----
  const float s1i = s1s[i0 + wvw * 16 + wl];

  f32x4 acc[8];
  f32x4 accl = (f32x4){0.f, 0.f, 0.f, 0.f};
#pragma unroll
  for (int f = 0; f < 8; ++f) acc[f] = (f32x4){0.f, 0.f, 0.f, 0.f};
  short8 ones;
#pragma unroll
  for (int e = 0; e < 8; ++e) ones[e] = (short)0x3F80;  // bf16 1.0

  for (int jj = 0; jj < 16; ++jj) {
    const int jb = jj * 32 + 8 * lg;  // this lane's 8 consecutive j's
    float sv[8];
    *reinterpret_cast<float4*>(&sv[0]) = *reinterpret_cast<const float4*>(&s2s[jb]);
    *reinterpret_cast<float4*>(&sv[4]) = *reinterpret_cast<const float4*>(&s2s[jb + 4]);
    float p[8];
#pragma unroll
    for (int e = 0; e < 8; ++e) {
      const float u = s1i + sv[e];
      p[e] = v_exp2(fmaxf(u, ALPHA * u));   // no max subtraction (proven R9-R22)
    }
    short8 af;
    unsigned* au = reinterpret_cast<unsigned*>(&af);
    au[0] = pk_bf16(p[0], p[1]); au[1] = pk_bf16(p[2], p[3]);
    au[2] = pk_bf16(p[4], p[5]); au[3] = pk_bf16(p[6], p[7]);

    const ushort* tb = tile + (size_t)(jj * 4 + lg) * 129 * 8;
    __builtin_amdgcn_s_setprio(1);     // favor this wave's MFMA cluster
#pragma unroll
    for (int f = 0; f < 8; ++f) {
      const short8 bfr = *reinterpret_cast<const short8*>(tb + (16 * f + wl) * 8);
      acc[f] = __builtin_amdgcn_mfma_f32_16x16x32_bf16(af, bfr, acc[f], 0, 0, 0);
    }
    accl = __builtin_amdgcn_mfma_f32_16x16x32_bf16(af, ones, accl, 0, 0, 0);
    __builtin_amdgcn_s_setprio(0);
  }

  // ---- P6: epilogue — sigmoid via exp2 + v_rcp; non-temporal f32x4 stores ----
  float invl[4];
#pragma unroll
  for (int m = 0; m < 4; ++m) invl[m] = LOG2E * v_rcp(accl[m]);
  const int ibase = i0 + wvw * 16 + lg * 4;
  float* outb = out + (size_t)b * (Ww * Nn);
#pragma unroll
  for (int f = 0; f < 8; ++f) {
    f32x4 o;
    o[0] = v_rcp(1.f + v_exp2(-(acc[f][0] * invl[0])));
    o[1] = v_rcp(1.f + v_exp2(-(acc[f][1] * invl[1])));
    o[2] = v_rcp(1.f + v_exp2(-(acc[f][2] * invl[2])));
    o[3] = v_rcp(1.f + v_exp2(-(acc[f][3] * invl[3])));
    __builtin_nontemporal_store(o, reinterpret_cast<f32x4*>(outb + (16 * f + wl) * Nn + ibase));
  }
}

extern "C" void kernel_launch(void* const* d_in, const int* in_sizes, int n_in,
                              void* d_out, int out_size, void* d_ws, size_t ws_size,
                              hipStream_t stream) {
  const float* x    = (const float*)d_in[0];  // (128,128,512)
  const float* Wfc  = (const float*)d_in[1];  // (128,128)
  const float* bfc  = (const float*)d_in[2];  // (128,)
  const float* attn = (const float*)d_in[3];  // (256,1)
  float* out = (float*)d_out;                 // (128,128,512)

  (void)hipFuncSetAttribute(reinterpret_cast<const void*>(&attn_p),
                            hipFuncAttributeMaxDynamicSharedMemorySize, SMEM15);
  attn_p<<<256, 1024, SMEM15, stream>>>(x, Wfc, bfc, attn, out);
}

// Round 25
// 25.885 us; speedup vs baseline: 1.0156x; 1.0156x over previous
//
#include <hip/hip_runtime.h>

#define Bb 128
#define Ww 128
#define Nn 512
#define ALPHA 0.2f
#define LOG2E 1.44269504088896340736f

typedef __attribute__((ext_vector_type(8))) short short8;
typedef __attribute__((ext_vector_type(4))) float f32x4;

// v_cvt_pk_bf16_f32: packs (lo,hi) -> u32 of 2 bf16 (RNE; proven R9-R24)
__device__ __forceinline__ unsigned pk_bf16(float lo, float hi) {
  unsigned r;
  asm("v_cvt_pk_bf16_f32 %0, %1, %2" : "=v"(r) : "v"(lo), "v"(hi));
  return r;
}

// v_exp_f32 computes 2^x on gfx950 (proven R13-R24)
__device__ __forceinline__ float v_exp2(float x) {
  float r;
  asm("v_exp_f32 %0, %1" : "=v"(r) : "v"(x));
  return r;
}

// v_rcp_f32: ~1ulp reciprocal (proven R18-R24)
__device__ __forceinline__ float v_rcp(float x) {
  float r;
  asm("v_rcp_f32 %0, %1" : "=v"(r) : "v"(x));
  return r;
}

// ---- dynamic LDS layout (bytes) ----
#define T_OFF   0
#define T_BYTES (64 * 129 * 8 * 2)     // ushort tile[64 jg][129 w][8] = 132096
#define SR_OFF  (T_OFF + T_BYTES)      // float sred[4096] = 16384
#define S1_OFF  (SR_OFF + 16384)       // float s1s[512]   = 2048
#define S2_OFF  (S1_OFF + 2048)        // float s2s[512]   = 2048
#define CV_OFF  (S2_OFF + 2048)        // float cvs[129]   (pad 528)
#define CP_OFF  (CV_OFF + 528)         // float cpart[1024] = 4096
#define SMEM13  (CP_OFF + 4096)        // 157200 < 163840

// One block = (batch b, i-half). 1024 threads = 16 waves = 4 waves/SIMD.
// Best-measured structure (R20/R22, 25.9us, reproduced twice):
//  - Wfc issued oldest, x second -> cvec FMAs wait at vmcnt(16) and run UNDER
//    the x fetch (in-order VMEM retirement exploited in the right direction);
//  - s2 partials reuse the register-held x (no reload);
//  - exp2-folded no-max softmax (lrelu commutes with positive log2e scale);
//  - softmax denominators via MFMA x ones (D[r,.] = rowsum(P));
//  - v_rcp epilogue; conflict-free LDS tile; XCD-paired block decode.
__launch_bounds__(1024, 1)
__global__ void attn_m(const float* __restrict__ x, const float* __restrict__ Wfc,
                       const float* __restrict__ bfc, const float* __restrict__ attn,
                       float* __restrict__ out) {
  extern __shared__ char smem[];
  ushort* tile  = (ushort*)(smem + T_OFF);
  float*  sred  = (float*)(smem + SR_OFF);
  float*  s1s   = (float*)(smem + S1_OFF);
  float*  s2s   = (float*)(smem + S2_OFF);
  float*  cvs   = (float*)(smem + CV_OFF);
  float*  cpart = (float*)(smem + CP_OFF);

  const int bid = blockIdx.x;
  const int xcd = bid & 7, idx = bid >> 3;
  const int b  = xcd * 16 + (idx >> 1);      // sibling i-half blocks share an XCD/L2
  const int i0 = (idx & 1) * 256;
  const int t  = threadIdx.x;                // 0..1023
  const int wvw = t >> 6;                    // wave 0..15
  const int lane = t & 63;
  const int wl = lane & 15, lg = lane >> 4;
  const int g  = t >> 7;                     // row-group 0..7 (wave-uniform)
  const int q2 = t & 127;                    // col-slice (4 floats)
  const float* xb = x + (size_t)b * (Ww * Nn);

  // ---- issue group 1 (oldest): Wfc column slice + c0 inputs ----
  float wreg[16];
#pragma unroll
  for (int vi = 0; vi < 16; ++vi)
    wreg[vi] = Wfc[(size_t)(g * 16 + vi) * Ww + q2];
  float c0p = 0.f;
  if (t < 64)
    c0p = fmaf(bfc[t], attn[Ww + t], bfc[t + 64] * attn[Ww + 64 + t]);
  __builtin_amdgcn_sched_barrier(0);   // pin: group 1 issued before x

  // ---- issue group 2: ALL 16 x float4 loads (rows g+8k, cols 4*q2) ----
  float4 L[16];
#pragma unroll
  for (int k = 0; k < 16; ++k)
    L[k] = *reinterpret_cast<const float4*>(xb + (size_t)(g + 8 * k) * Nn + 4 * q2);
  __builtin_amdgcn_sched_barrier(0);   // pin: x issued before wreg consumption

  // ---- cvec partials from wreg: waits vmcnt(16), x stays in flight ----
  {
    float cp = 0.f;
#pragma unroll
    for (int vi = 0; vi < 16; ++vi)
      cp = fmaf(attn[Ww + g * 16 + vi], wreg[vi], cp);   // attn[..] wave-uniform
    cpart[t] = cp;                     // partial for col q2 from group g
    if (t < 64) {
      float cc = c0p;
#pragma unroll
      for (int off = 32; off; off >>= 1) cc += __shfl_xor(cc, off);
      if (t == 0) cvs[Ww] = cc;
    }
  }

  // ---- drain x: s1 partials + bf16 tile write ----
  float s1p[4] = {0.f, 0.f, 0.f, 0.f};
#pragma unroll
  for (int k = 0; k < 16; ++k) {
    const int w = g + 8 * k;
    const float aw = attn[w];          // wave-uniform -> s_load
    const float4 v = L[k];
    s1p[0] = fmaf(v.x, aw, s1p[0]); s1p[1] = fmaf(v.y, aw, s1p[1]);
    s1p[2] = fmaf(v.z, aw, s1p[2]); s1p[3] = fmaf(v.w, aw, s1p[3]);
    uint2 pk;
    pk.x = pk_bf16(v.x, v.y);
    pk.y = pk_bf16(v.z, v.w);
    *reinterpret_cast<uint2*>(tile + ((size_t)(q2 >> 1) * 129 + w) * 8 + (q2 & 1) * 4) = pk;
  }
  *reinterpret_cast<f32x4*>(&sred[t * 4]) = (f32x4){s1p[0], s1p[1], s1p[2], s1p[3]};
  __syncthreads();                     // BAR1: cpart + sred(s1) + tile visible

  // ---- cvs reduce (t<128) + s1 reduce (t<512) ----
  if (t < Ww) {
    float s = 0.f;
#pragma unroll
    for (int j = 0; j < 8; ++j) s += cpart[t + 128 * j];
    cvs[t] = s;
  }
  float red = 0.f;
  if (t < 512) {
#pragma unroll
    for (int j = 0; j < 8; ++j) red += sred[j * 512 + t];
  }
  __syncthreads();                     // BAR2: sred(s1) reads done; cvs visible
  if (t < 512) s1s[t] = red * LOG2E;

  // ---- s2 partials from the register-held x (no reload) ----
  float s2p[4] = {0.f, 0.f, 0.f, 0.f};
#pragma unroll
  for (int k = 0; k < 16; ++k) {
    const int w = g + 8 * k;
    const float cw = cvs[w];
    const float4 v = L[k];
    s2p[0] = fmaf(v.x, cw, s2p[0]); s2p[1] = fmaf(v.y, cw, s2p[1]);
    s2p[2] = fmaf(v.z, cw, s2p[2]); s2p[3] = fmaf(v.w, cw, s2p[3]);
  }
  *reinterpret_cast<f32x4*>(&sred[t * 4]) = (f32x4){s2p[0], s2p[1], s2p[2], s2p[3]};
  __syncthreads();                     // BAR3: sred(s2) visible
  if (t < 512) {
    float d = 0.f;
#pragma unroll
    for (int j = 0; j < 8; ++j) d += sred[j * 512 + t];
    s2s[t] = (d + cvs[Ww]) * LOG2E;
  }
  __syncthreads();                     // BAR4: s2s ready

  // ---- P4: MFMA loop; exp2 no-max softmax; denominators via MFMA x ones ----
  const float s1i = s1s[i0 + wvw * 16 + wl];

  f32x4 acc[8];
  f32x4 accl = (f32x4){0.f, 0.f, 0.f, 0.f};
#pragma unroll
  for (int f = 0; f < 8; ++f) acc[f] = (f32x4){0.f, 0.f, 0.f, 0.f};
  short8 ones;
#pragma unroll
  for (int e = 0; e < 8; ++e) ones[e] = (short)0x3F80;  // bf16 1.0

  for (int jj = 0; jj < 16; ++jj) {
    const int jb = jj * 32 + 8 * lg;  // this lane's 8 consecutive j's
    float sv[8];
    *reinterpret_cast<float4*>(&sv[0]) = *reinterpret_cast<const float4*>(&s2s[jb]);
    *reinterpret_cast<float4*>(&sv[4]) = *reinterpret_cast<const float4*>(&s2s[jb + 4]);
    float p[8];
#pragma unroll
    for (int e = 0; e < 8; ++e) {
      const float u = s1i + sv[e];
      p[e] = v_exp2(fmaxf(u, ALPHA * u));   // no max subtraction (proven R9-R24)
    }
    short8 af;
    unsigned* au = reinterpret_cast<unsigned*>(&af);
    au[0] = pk_bf16(p[0], p[1]); au[1] = pk_bf16(p[2], p[3]);
    au[2] = pk_bf16(p[4], p[5]); au[3] = pk_bf16(p[6], p[7]);

    const ushort* tb = tile + (size_t)(jj * 4 + lg) * 129 * 8;
#pragma unroll
    for (int f = 0; f < 8; ++f) {
      const short8 bfr = *reinterpret_cast<const short8*>(tb + (16 * f + wl) * 8);
      acc[f] = __builtin_amdgcn_mfma_f32_16x16x32_bf16(af, bfr, acc[f], 0, 0, 0);
    }
    accl = __builtin_amdgcn_mfma_f32_16x16x32_bf16(af, ones, accl, 0, 0, 0);
  }

  // ---- P6: epilogue — sigmoid via exp2 + v_rcp ----
  float invl[4];
#pragma unroll
  for (int m = 0; m < 4; ++m) invl[m] = LOG2E * v_rcp(accl[m]);
  const int ibase = i0 + wvw * 16 + lg * 4;
  float* outb = out + (size_t)b * (Ww * Nn);
#pragma unroll
  for (int f = 0; f < 8; ++f) {
    float4 o;
    o.x = v_rcp(1.f + v_exp2(-(acc[f][0] * invl[0])));
    o.y = v_rcp(1.f + v_exp2(-(acc[f][1] * invl[1])));
    o.z = v_rcp(1.f + v_exp2(-(acc[f][2] * invl[2])));
    o.w = v_rcp(1.f + v_exp2(-(acc[f][3] * invl[3])));
    *reinterpret_cast<float4*>(outb + (16 * f + wl) * Nn + ibase) = o;
  }
}

extern "C" void kernel_launch(void* const* d_in, const int* in_sizes, int n_in,
                              void* d_out, int out_size, void* d_ws, size_t ws_size,
                              hipStream_t stream) {
  const float* x    = (const float*)d_in[0];  // (128,128,512)
  const float* Wfc  = (const float*)d_in[1];  // (128,128)
  const float* bfc  = (const float*)d_in[2];  // (128,)
  const float* attn = (const float*)d_in[3];  // (256,1)
  float* out = (float*)d_out;                 // (128,128,512)

  (void)hipFuncSetAttribute(reinterpret_cast<const void*>(&attn_m),
                            hipFuncAttributeMaxDynamicSharedMemorySize, SMEM13);
  attn_m<<<256, 1024, SMEM13, stream>>>(x, Wfc, bfc, attn, out);
}